// Round 11
// baseline (256.647 us; speedup 1.0000x reference)
//
#include <hip/hip_runtime.h>
#include <hip/hip_bf16.h>

typedef float fx4  __attribute__((ext_vector_type(4)));
typedef float fx16 __attribute__((ext_vector_type(16)));
typedef short s16x8 __attribute__((ext_vector_type(8)));

#define NSEQ 2048
#define DM   1024
#define NH   16
#define DH   64
#define MROWS 4096               // B * NSEQ
#define NWORDS (2 * NSEQ * (NSEQ / 64))   // 131072 packed-mask words

// QK scale with log2(e) folded in: softmax runs in exp2 domain.
#define QK_SCALE (0.125f * 1.44269504088896f)

__device__ __forceinline__ unsigned short f2bf(float f) {
    union { float f; unsigned u; } c; c.f = f;
    unsigned u = c.u;
    unsigned r = u + 0x7FFFu + ((u >> 16) & 1u);   // round-to-nearest-even
    return (unsigned short)(r >> 16);
}

__device__ __forceinline__ float exp2_fast(float x) {
#if __has_builtin(__builtin_amdgcn_exp2f)
    return __builtin_amdgcn_exp2f(x);
#else
    return exp2f(x);
#endif
}

// hardware packed f32->bf16 (RNE): dst.lo = bf16(a), dst.hi = bf16(b)
__device__ __forceinline__ unsigned cvt_pk_bf16(float a, float b) {
    unsigned r;
    asm("v_cvt_pk_bf16_f32 %0, %1, %2" : "=v"(r) : "v"(a), "v"(b));
    return r;
}

__device__ __forceinline__ fx4 zero4() {
    fx4 z; z[0] = 0.f; z[1] = 0.f; z[2] = 0.f; z[3] = 0.f; return z;
}

__device__ __forceinline__ fx16 zero16() {
    fx16 z;
#pragma unroll
    for (int i = 0; i < 16; i++) z[i] = 0.f;
    return z;
}

// async global->LDS, 16B per lane. LDS dest = wave-uniform base + lane*16.
__device__ __forceinline__ void gload16(const void* g, void* l) {
    __builtin_amdgcn_global_load_lds(
        (const __attribute__((address_space(1))) unsigned int*)g,
        (__attribute__((address_space(3))) unsigned int*)l,
        16, 0, 0);
}

// ---------------- fp32 -> bf16 conversion ----------------
__global__ void cvt_kernel(const float* __restrict__ in,
                           unsigned short* __restrict__ out, int n4) {
    int i = blockIdx.x * blockDim.x + threadIdx.x;
    if (i >= n4) return;
    float4 v = reinterpret_cast<const float4*>(in)[i];
    ushort4 o;
    o.x = f2bf(v.x); o.y = f2bf(v.y); o.z = f2bf(v.z); o.w = f2bf(v.w);
    reinterpret_cast<ushort4*>(out)[i] = o;
}

// 4 weight matrices in one launch; grid MUST be (1024, 4): DM*DM/4/256 = 1024.
__global__ void cvt4_kernel(const float* __restrict__ w0, const float* __restrict__ w1,
                            const float* __restrict__ w2, const float* __restrict__ w3,
                            unsigned short* __restrict__ o0, unsigned short* __restrict__ o1,
                            unsigned short* __restrict__ o2, unsigned short* __restrict__ o3) {
    const float* in; unsigned short* out;
    switch (blockIdx.y) {
        case 0:  in = w0; out = o0; break;
        case 1:  in = w1; out = o1; break;
        case 2:  in = w2; out = o2; break;
        default: in = w3; out = o3; break;
    }
    int i = blockIdx.x * blockDim.x + threadIdx.x;
    float4 v = reinterpret_cast<const float4*>(in)[i];
    ushort4 o;
    o.x = f2bf(v.x); o.y = f2bf(v.y); o.z = f2bf(v.z); o.w = f2bf(v.w);
    reinterpret_cast<ushort4*>(out)[i] = o;
}

// ---------------- mask dtype detection ----------------
// int32 0/1 data can never make a u32 word > 1; packed bool bytes will.
__global__ void mask_detect(const unsigned int* __restrict__ m, int* __restrict__ flag) {
    unsigned mx = 0;
    int stride = gridDim.x * blockDim.x;
    for (int i = blockIdx.x * blockDim.x + threadIdx.x; i < (2 * NSEQ * NSEQ) / 4; i += stride) {
        unsigned v = m[i];
        mx = v > mx ? v : mx;
    }
    if (__any(mx > 1u)) {
        if ((threadIdx.x & 63) == 0) atomicOr(flag, 1);
    }
}

// ---------------- mask bit-pack (32x32 layout) ----------------
// packed[w] covers keys kw*64..+63 of global row bq (w = bq*32 + kw).
// Bit p <-> key (p&3) + 8*((p>>2)&3) + 4*(p>>5) + 32*((p>>4)&1):
// attn lane (hi = lane>>5) extracts u32 = pw >> (32*hi); bit (16*kh + reg)
// corresponds to S^T reg `reg` of key-half kh.
__global__ void mask_pack(const void* __restrict__ mask, const int* __restrict__ mflag,
                          unsigned long long* __restrict__ packed) {
    const int flg  = mflag[0];
    const int lane = threadIdx.x & 63;
    const int wpb  = blockDim.x >> 6;
    const int perm = (lane & 3) + 8 * ((lane >> 2) & 3) + 4 * (lane >> 5) + 32 * ((lane >> 4) & 1);
    size_t w = (size_t)blockIdx.x * wpb + (threadIdx.x >> 6);
    const size_t stride = (size_t)gridDim.x * wpb;
    for (; w < NWORDS; w += stride) {
        size_t elem = (w >> 5) * (size_t)NSEQ + (size_t)(w & 31) * 64 + perm;
        int mv = flg ? (int)((const unsigned char*)mask)[elem]
                     : ((const int*)mask)[elem];
        unsigned long long bits = __ballot(mv != 0);
        if (lane == 0) packed[w] = bits;
    }
}

// ---------------- fused QKV GEMM (m97 staging; UNCHANGED) ----------------
__global__ __launch_bounds__(256) void gemm_qkv(
        const unsigned short* __restrict__ A,
        const unsigned short* __restrict__ Wq,
        const unsigned short* __restrict__ Wk,
        const unsigned short* __restrict__ Wv,
        unsigned short* __restrict__ Qh,     // [B,H,N,64], pre-scaled by QK_SCALE
        unsigned short* __restrict__ Kh,     // [B,H,N,64]
        unsigned short* __restrict__ VhT) {  // [B,H,64,N]
    __shared__ unsigned short As[128 * 32];
    __shared__ unsigned short Bs[128 * 32];

    const int tid  = threadIdx.x;
    const int lane = tid & 63;
    const int w    = tid >> 6;
    const int lr   = lane & 15;
    const int lg   = lane >> 4;
    const int wr   = (w >> 1) * 64;
    const int wc   = (w & 1) * 64;
    const int rowbase = blockIdx.y * 128;
    const int seg     = blockIdx.x >> 3;              // 0,1,2
    const int cb      = (blockIdx.x & 7) * 128;
    const unsigned short* W = seg == 0 ? Wq : (seg == 1 ? Wk : Wv);
    const float scale = seg == 0 ? QK_SCALE : 1.0f;

    fx4 acc[4][4];
#pragma unroll
    for (int i = 0; i < 4; i++)
#pragma unroll
        for (int j = 0; j < 4; j++) acc[i][j] = zero4();

    for (int k0 = 0; k0 < DM; k0 += 32) {
        __syncthreads();
#pragma unroll
        for (int i = 0; i < 2; i++) {
            int j = i * 256 + w * 64 + lane;
            int r = j >> 2, c8 = (j & 3) * 8;
            gload16(A + (size_t)(rowbase + r) * DM + k0 + c8,
                    As + (size_t)(i * 256 + w * 64) * 8);
            gload16(W + (size_t)(cb + r) * DM + k0 + c8,
                    Bs + (size_t)(i * 256 + w * 64) * 8);
        }
        __syncthreads();

        s16x8 af[4], bf[4];
#pragma unroll
        for (int mi = 0; mi < 4; mi++)
            af[mi] = *reinterpret_cast<const s16x8*>(&As[(wr + mi * 16 + lr) * 32 + 8 * lg]);
#pragma unroll
        for (int ni = 0; ni < 4; ni++)
            bf[ni] = *reinterpret_cast<const s16x8*>(&Bs[(wc + ni * 16 + lr) * 32 + 8 * lg]);
#pragma unroll
        for (int mi = 0; mi < 4; mi++)
#pragma unroll
            for (int ni = 0; ni < 4; ni++)
                acc[mi][ni] = __builtin_amdgcn_mfma_f32_16x16x32_bf16(af[mi], bf[ni], acc[mi][ni], 0, 0, 0);
    }

#pragma unroll
    for (int mi = 0; mi < 4; mi++) {
#pragma unroll
        for (int ni = 0; ni < 4; ni++) {
#pragma unroll
            for (int v = 0; v < 4; v++) {
                int m    = rowbase + wr + mi * 16 + lg * 4 + v;
                int cseg = cb + wc + ni * 16 + lr;
                float val = acc[mi][ni][v] * scale;
                int b = m >> 11, nseq = m & 2047;
                int h = cseg >> 6, dh = cseg & 63;
                if (seg < 2) {
                    unsigned short* dst = seg == 0 ? Qh : Kh;
                    dst[((size_t)(b * NH + h) * NSEQ + nseq) * DH + dh] = f2bf(val);
                } else {
                    VhT[((size_t)(b * NH + h) * DH + dh) * NSEQ + nseq] = f2bf(val);
                }
            }
        }
    }
}

// ---------------- output GEMM: 64x128 tile (UNCHANGED) ----------------
__global__ __launch_bounds__(256) void gemm_out(
        const unsigned short* __restrict__ A,    // Obuf bf16 [4096][1024]
        const unsigned short* __restrict__ W,
        float* __restrict__ out,
        const float* __restrict__ bias) {
    __shared__ unsigned short As[64 * 32];
    __shared__ unsigned short Bs[128 * 32];

    const int tid  = threadIdx.x;
    const int lane = tid & 63;
    const int w    = tid >> 6;
    const int lr   = lane & 15;
    const int lg   = lane >> 4;
    const int wr   = (w >> 1) * 32;          // wave rows: 0 / 32
    const int wc   = (w & 1) * 64;           // wave cols: 0 / 64
    const int rowbase = blockIdx.y * 64;
    const int colbase = blockIdx.x * 128;

    fx4 acc[2][4];
#pragma unroll
    for (int i = 0; i < 2; i++)
#pragma unroll
        for (int j = 0; j < 4; j++) acc[i][j] = zero4();

    for (int k0 = 0; k0 < DM; k0 += 32) {
        __syncthreads();
        {
            int j = tid;
            int r = j >> 2, c8 = (j & 3) * 8;
            gload16(A + (size_t)(rowbase + r) * DM + k0 + c8,
                    As + (size_t)(w * 64) * 8);
            gload16(W + (size_t)(colbase + r) * DM + k0 + c8,
                    Bs + (size_t)(w * 64) * 8);
            int r2 = 64 + (j >> 2);
            gload16(W + (size_t)(colbase + r2) * DM + k0 + c8,
                    Bs + (size_t)(256 + w * 64) * 8);
        }
        __syncthreads();

        s16x8 af[2], bf[4];
#pragma unroll
        for (int mi = 0; mi < 2; mi++)
            af[mi] = *reinterpret_cast<const s16x8*>(&As[(wr + mi * 16 + lr) * 32 + 8 * lg]);
#pragma unroll
        for (int ni = 0; ni < 4; ni++)
            bf[ni] = *reinterpret_cast<const s16x8*>(&Bs[(wc + ni * 16 + lr) * 32 + 8 * lg]);
#pragma unroll
        for (int mi = 0; mi < 2; mi++)
#pragma unroll
            for (int ni = 0; ni < 4; ni++)
                acc[mi][ni] = __builtin_amdgcn_mfma_f32_16x16x32_bf16(af[mi], bf[ni], acc[mi][ni], 0, 0, 0);
    }

#pragma unroll
    for (int mi = 0; mi < 2; mi++)
#pragma unroll
        for (int ni = 0; ni < 4; ni++)
#pragma unroll
            for (int v = 0; v < 4; v++) {
                int m = rowbase + wr + mi * 16 + lg * 4 + v;
                int c = colbase + wc + ni * 16 + lr;
                out[(size_t)m * DM + c] = acc[mi][ni][v] + bias[c];
            }
}

// ---------------- flash attention: 32x32 MFMA + in-block KV split ------------
// grid 512 (XCD-swizzled 8x64), 8 waves (512 thr). Group g = wave>>2 handles
// KV tiles g*16..g*16+15; wave w&3 owns q rows (w&3)*32..+31 (both groups).
// End: flash-merge group 1's (po,m,l) into group 0 via LDS; group 0 writes O.
__global__ __launch_bounds__(512) void attn_kernel(
        const unsigned short* __restrict__ Qh,   // [B,H,N,64] bf16 (scaled by QK_SCALE)
        const unsigned short* __restrict__ Kh,   // [B,H,N,64] bf16
        const unsigned short* __restrict__ VhT,  // [B,H,64,N] bf16
        const unsigned long long* __restrict__ Mp, // packed mask [B*N][32]
        unsigned short* __restrict__ Obuf) {     // [B,N,1024] bf16
    __shared__ unsigned short Ks[2][2][64 * 64]; // [group][dbuf], 32 KB
    __shared__ unsigned short Vs[2][2][64 * 64]; // [group][dbuf], 32 KB

    const int tid  = threadIdx.x;
    const int lane = tid & 63;
    const int w8   = tid >> 6;       // 0..7
    const int grp  = w8 >> 2;        // 0,1 = KV half
    const int w    = w8 & 3;         // wave within group: q-tile owner
    const int gt   = tid & 255;      // thread within group
    const int l31  = lane & 31;
    const int hi   = lane >> 5;

    // bijective XCD swizzle: 512 = 8 XCDs x 64 contiguous blocks
    const int wg    = ((blockIdx.x & 7) << 6) | (blockIdx.x >> 3);
    const int qbase = (wg & 15) << 7;            // 16 q-tiles of 128
    const int bh    = wg >> 4;                   // 0..31
    const int b     = bh >> 4;
    const int h     = bh & 15;

    // Q fragment (B-operand of 32x32x16): lane holds Q[q = w*32+l31][dh = s*16+hi*8+j]
    s16x8 qf[4];
    const size_t qrow = (size_t)bh * NSEQ + qbase + w * 32 + l31;
#pragma unroll
    for (int s = 0; s < 4; s++)
        qf[s] = *reinterpret_cast<const s16x8*>(Qh + qrow * DH + s * 16 + hi * 8);

    float mreg = -3.0e38f, lrow = 0.f;
    fx16 po[2];
    po[0] = zero16(); po[1] = zero16();

    const size_t mbase = ((size_t)b * NSEQ + qbase + w * 32 + l31) * (NSEQ / 64);

    // stage tile kv0 into this group's buffer d (linear dest + inv-swz source)
    auto stage = [&](int d, int kv0) {
#pragma unroll
        for (int i = 0; i < 2; i++) {
            int u  = i * 256 + gt;               // dest chunk 0..511 (group-local)
            int r  = u >> 3, cs = u & 7;
            int cu = cs ^ (r & 7);
            gload16(Kh + ((size_t)bh * NSEQ + kv0 + r) * DH + cu * 8,
                    &Ks[grp][d][(size_t)(i * 256 + w * 64) * 8]);
            gload16(VhT + ((size_t)bh * DH + r) * NSEQ + kv0 + cu * 8,
                    &Vs[grp][d][(size_t)(i * 256 + w * 64) * 8]);
        }
    };

    const int kvbase = grp << 10;                // grp*16 tiles * 64
    stage(0, kvbase);
    __syncthreads();

    for (int it = 0; it < 16; it++) {
        const int cur = it & 1;
        if (it < 15) stage(cur ^ 1, kvbase + ((it + 1) << 6));   // prefetch next

        // this lane's 32 mask bits: u32 half of the q-row's packed word
        unsigned long long pwm = Mp[mbase + grp * 16 + it];
        unsigned m32 = (unsigned)(pwm >> (hi * 32));

        // S^T = K · Q^T : 8 MFMAs of 32x32x16 (2 key-halves x 4 dh-steps)
        fx16 sx[2];
        __builtin_amdgcn_s_setprio(1);
#pragma unroll
        for (int kh = 0; kh < 2; kh++) {
            sx[kh] = zero16();
            int r = kh * 32 + l31;
#pragma unroll
            for (int s = 0; s < 4; s++) {
                int cs = (2 * s + hi) ^ (r & 7);
                s16x8 kf = *reinterpret_cast<const s16x8*>(&Ks[grp][cur][r * 64 + cs * 8]);
                sx[kh] = __builtin_amdgcn_mfma_f32_32x32x16_bf16(kf, qf[s], sx[kh], 0, 0, 0);
            }
        }
        __builtin_amdgcn_s_setprio(0);

        // mask + in-register max over this lane's 32 keys
        float tmax = -3.0e38f;
#pragma unroll
        for (int kh = 0; kh < 2; kh++)
#pragma unroll
            for (int reg = 0; reg < 16; reg++) {
                float sv = (m32 & (1u << (kh * 16 + reg))) ? -3.0e38f : sx[kh][reg];
                sx[kh][reg] = sv;
                tmax = fmaxf(tmax, sv);
            }
        tmax = fmaxf(tmax, __shfl_xor(tmax, 32));

        // defer-max: rescale only when the row max grows by > 8 (exp2 domain)
        if (__any(tmax > mreg + 8.0f)) {
            float mn = fmaxf(mreg, tmax);
            float sc = exp2_fast(mreg - mn);
            mreg = mn;
            lrow *= sc;
#pragma unroll
            for (int reg = 0; reg < 16; reg++) {
                int qr = (reg & 3) + 8 * (reg >> 2) + 4 * hi;
                float scq = __shfl(sc, qr);
                po[0][reg] *= scq;
                po[1][reg] *= scq;
            }
        }

        // exp2 + row sum (in-register + 1 shfl)
        float psum = 0.f;
#pragma unroll
        for (int kh = 0; kh < 2; kh++)
#pragma unroll
            for (int reg = 0; reg < 16; reg++) {
                float p = exp2_fast(sx[kh][reg] - mreg);
                sx[kh][reg] = p;
                psum += p;
            }
        psum += __shfl_xor(psum, 32);
        lrow += psum;

        // O += P·V : P A-fragment built in registers via cvt_pk + permlane32_swap
        __builtin_amdgcn_s_setprio(1);
#pragma unroll
        for (int ks = 0; ks < 4; ks++) {
            const int kh = ks >> 1, rb = (ks & 1) * 8;
            unsigned o0w0 = cvt_pk_bf16(sx[kh][rb + 0], sx[kh][rb + 1]);
            unsigned o0w1 = cvt_pk_bf16(sx[kh][rb + 2], sx[kh][rb + 3]);
            unsigned o1w0 = cvt_pk_bf16(sx[kh][rb + 4], sx[kh][rb + 5]);
            unsigned o1w1 = cvt_pk_bf16(sx[kh][rb + 6], sx[kh][rb + 7]);
            asm("v_permlane32_swap_b32 %0, %1" : "+v"(o0w0), "+v"(o1w0));
            asm("v_permlane32_swap_b32 %0, %1" : "+v"(o0w1), "+v"(o1w1));
            union { unsigned u[4]; s16x8 v; } pk;
            pk.u[0] = o0w0; pk.u[1] = o0w1; pk.u[2] = o1w0; pk.u[3] = o1w1;
#pragma unroll
            for (int dt = 0; dt < 2; dt++) {
                int r  = dt * 32 + l31;
                int cs = (2 * ks + hi) ^ (r & 7);
                s16x8 vf = *reinterpret_cast<const s16x8*>(&Vs[grp][cur][r * 64 + cs * 8]);
                po[dt] = __builtin_amdgcn_mfma_f32_32x32x16_bf16(pk.v, vf, po[dt], 0, 0, 0);
            }
        }
        __builtin_amdgcn_s_setprio(0);

        __syncthreads();   // drains prefetch vmcnt; flips buffer
    }

    // ---- flash merge: group 1 -> LDS, group 0 combines + writes ----
    // exPo reuses Ks (32 KB = 4 waves x 64 lanes x 32 f32, lane-contiguous);
    // exM/exL reuse Vs (2 KB).
    float* exPo = (float*)Ks;
    float* exML = (float*)Vs;
    if (grp == 1) {
#pragma unroll
        for (int dt = 0; dt < 2; dt++)
#pragma unroll
            for (int reg = 0; reg < 16; reg++)
                exPo[w * 64 + lane + (dt * 16 + reg) * 256] = po[dt][reg];
        exML[w * 64 + lane] = mreg;
        exML[1024 + w * 64 + lane] = lrow;
    }
    __syncthreads();
    if (grp == 0) {
        float mB = exML[w * 64 + lane];
        float lB = exML[1024 + w * 64 + lane];
        float M  = fmaxf(mreg, mB);
        float sA = exp2_fast(mreg - M);
        float sB = exp2_fast(mB - M);
        lrow = sA * lrow + sB * lB;
#pragma unroll
        for (int reg = 0; reg < 16; reg++) {
            int qr = (reg & 3) + 8 * (reg >> 2) + 4 * hi;
            float sAq = __shfl(sA, qr);
            float sBq = __shfl(sB, qr);
            po[0][reg] = sAq * po[0][reg] + sBq * exPo[w * 64 + lane + reg * 256];
            po[1][reg] = sAq * po[1][reg] + sBq * exPo[w * 64 + lane + (16 + reg) * 256];
        }

        // epilogue: po[dt][reg] = O[q = qbase+w*32+qr][d = dt*32+l31]
        float inv = 1.0f / lrow;
#pragma unroll
        for (int reg = 0; reg < 16; reg++) {
            int qr = (reg & 3) + 8 * (reg >> 2) + 4 * hi;
            float invq = __shfl(inv, qr);
            int q = qbase + w * 32 + qr;
#pragma unroll
            for (int dt = 0; dt < 2; dt++) {
                int d = dt * 32 + l31;
                Obuf[((size_t)b * NSEQ + q) * DM + h * DH + d] = f2bf(po[dt][reg] * invq);
            }
        }
    }
}

// ---------------- launch ----------------
extern "C" void kernel_launch(void* const* d_in, const int* in_sizes, int n_in,
                              void* d_out, int out_size, void* d_ws, size_t ws_size,
                              hipStream_t stream) {
    const float* q    = (const float*)d_in[0];
    const void*  mask = (const void*)d_in[1];
    const float* Wq   = (const float*)d_in[2];
    const float* Wk   = (const float*)d_in[3];
    const float* Wv   = (const float*)d_in[4];
    const float* Wo   = (const float*)d_in[5];
    const float* bo   = (const float*)d_in[6];
    float* out = (float*)d_out;

    char* ws = (char*)d_ws;
    const size_t MB = 1024 * 1024;
    unsigned short* qbf  = (unsigned short*)(ws + 0);        // 8 MB (QKV phase)
    unsigned long long* packed = (unsigned long long*)(ws + 0); // 1 MB, reuses qbf AFTER gemm_qkv
    unsigned short* Wqb  = (unsigned short*)(ws + 8  * MB);  // 2 MB
    unsigned short* Wkb  = (unsigned short*)(ws + 10 * MB);  // 2 MB
    unsigned short* Wvb  = (unsigned short*)(ws + 12 * MB);  // 2 MB
    unsigned short* Wob  = (unsigned short*)(ws + 14 * MB);  // 2 MB
    unsigned short* Qh   = (unsigned short*)(ws + 16 * MB);  // 8 MB  [B,H,N,64]
    unsigned short* Kh   = (unsigned short*)(ws + 24 * MB);  // 8 MB  [B,H,N,64]
    unsigned short* VhT  = (unsigned short*)(ws + 32 * MB);  // 8 MB  [B,H,64,N]
    unsigned short* Obuf = (unsigned short*)(ws + 40 * MB);  // 8 MB  [B,N,1024] bf16
    int*            flag = (int*)(ws + 56 * MB);             // 4 B

    hipMemsetAsync(flag, 0, 4, stream);
    mask_detect<<<1024, 256, 0, stream>>>((const unsigned int*)mask, flag);

    cvt_kernel<<<4096, 256, 0, stream>>>(q, qbf, (2 * NSEQ * DM) / 4);
    cvt4_kernel<<<dim3(1024, 4), 256, 0, stream>>>(Wq, Wk, Wv, Wo, Wqb, Wkb, Wvb, Wob);

    gemm_qkv<<<dim3(24, 32), 256, 0, stream>>>(qbf, Wqb, Wkb, Wvb, Qh, Kh, VhT);

    // qbf is dead now; pack the mask into its space (1 MB)
    mask_pack<<<1024, 256, 0, stream>>>(mask, flag, packed);

    attn_kernel<<<512, 512, 0, stream>>>(Qh, Kh, VhT, packed, Obuf);

    gemm_out<<<dim3(8, 64), 256, 0, stream>>>(Obuf, Wob, out, bo);
}